// Round 9
// baseline (4316.544 us; speedup 1.0000x reference)
//
#include <hip/hip_runtime.h>

typedef unsigned short u16;
typedef __bf16 bf16_t;
typedef bf16_t bf16x8 __attribute__((ext_vector_type(8)));
typedef float f32x4 __attribute__((ext_vector_type(4)));
typedef unsigned int u32x4 __attribute__((ext_vector_type(4)));

#define DEV static __device__ __forceinline__
#define RLX __ATOMIC_RELAXED
#define AGT __HIP_MEMORY_SCOPE_AGENT

DEV u16 f2bf(float f){ unsigned u = __float_as_uint(f); return (u16)((u + 0x7fffu + ((u>>16)&1u))>>16); }
DEV float bf2f(u16 b){ return __uint_as_float(((unsigned)b)<<16); }
DEV float sigf(float x){ return 1.0f/(1.0f+__expf(-x)); }
DEV float tanhf_(float x){ float e = __expf(2.0f*x); return 1.0f - 2.0f/(e+1.0f); }

union FragU { bf16x8 v; u16 u[8]; u32x4 q; };

// ------------------------------------------------------------------
// Transport. IC flavor (sc0 sc1): cross-XCD coherent. L2 flavor (sc0):
// XCD-local L2 coherent (store write-through to L2, load bypasses L1) —
// used for h0/h1 ONLY when the site's 32 blocks share one XCD
// (runtime-verified). Sync counters are ALWAYS IC (R8-proven protocol).
// ------------------------------------------------------------------
#define DEF_LDG16(NAME, SC)                                            \
DEV void NAME(u32x4 r[16], const void* b0, const void* b1){            \
  asm volatile(                                                        \
    "global_load_dwordx4 %0,  %16, off " SC "\n\t"                     \
    "global_load_dwordx4 %1,  %16, off offset:64 " SC "\n\t"           \
    "global_load_dwordx4 %2,  %16, off offset:128 " SC "\n\t"          \
    "global_load_dwordx4 %3,  %16, off offset:192 " SC "\n\t"          \
    "global_load_dwordx4 %4,  %16, off offset:256 " SC "\n\t"          \
    "global_load_dwordx4 %5,  %16, off offset:320 " SC "\n\t"          \
    "global_load_dwordx4 %6,  %16, off offset:384 " SC "\n\t"          \
    "global_load_dwordx4 %7,  %16, off offset:448 " SC "\n\t"          \
    "global_load_dwordx4 %8,  %17, off " SC "\n\t"                     \
    "global_load_dwordx4 %9,  %17, off offset:64 " SC "\n\t"           \
    "global_load_dwordx4 %10, %17, off offset:128 " SC "\n\t"          \
    "global_load_dwordx4 %11, %17, off offset:192 " SC "\n\t"          \
    "global_load_dwordx4 %12, %17, off offset:256 " SC "\n\t"          \
    "global_load_dwordx4 %13, %17, off offset:320 " SC "\n\t"          \
    "global_load_dwordx4 %14, %17, off offset:384 " SC "\n\t"          \
    "global_load_dwordx4 %15, %17, off offset:448 " SC                 \
    : "=&v"(r[0]), "=&v"(r[1]), "=&v"(r[2]), "=&v"(r[3]),              \
      "=&v"(r[4]), "=&v"(r[5]), "=&v"(r[6]), "=&v"(r[7]),              \
      "=&v"(r[8]), "=&v"(r[9]), "=&v"(r[10]), "=&v"(r[11]),            \
      "=&v"(r[12]), "=&v"(r[13]), "=&v"(r[14]), "=&v"(r[15])           \
    : "v"(b0), "v"(b1) : "memory");                                    \
}
DEF_LDG16(ldg16_ic, "sc0 sc1")
DEF_LDG16(ldg16_l2, "sc0")

DEV void wait_vm16(){ asm volatile("s_waitcnt vmcnt(16)" ::: "memory"); __builtin_amdgcn_sched_barrier(0); }
DEV void wait_vm0(){ asm volatile("s_waitcnt vmcnt(0)" ::: "memory"); __builtin_amdgcn_sched_barrier(0); }

DEV void ldg8f_sc(u32x4 r[8], float& lv, const void* b0, const float* lp){
  asm volatile(
    "global_load_dwordx4 %0, %9, off sc0 sc1\n\t"
    "global_load_dwordx4 %1, %9, off offset:64 sc0 sc1\n\t"
    "global_load_dwordx4 %2, %9, off offset:128 sc0 sc1\n\t"
    "global_load_dwordx4 %3, %9, off offset:192 sc0 sc1\n\t"
    "global_load_dwordx4 %4, %9, off offset:256 sc0 sc1\n\t"
    "global_load_dwordx4 %5, %9, off offset:320 sc0 sc1\n\t"
    "global_load_dwordx4 %6, %9, off offset:384 sc0 sc1\n\t"
    "global_load_dwordx4 %7, %9, off offset:448 sc0 sc1\n\t"
    "global_load_dword %8, %10, off sc0 sc1\n\t"
    "s_waitcnt vmcnt(0)"
    : "=&v"(r[0]), "=&v"(r[1]), "=&v"(r[2]), "=&v"(r[3]),
      "=&v"(r[4]), "=&v"(r[5]), "=&v"(r[6]), "=&v"(r[7]), "=&v"(lv)
    : "v"(b0), "v"(lp) : "memory");
}
DEV float ldf_sc(const float* p){
  float r;
  asm volatile("global_load_dword %0, %1, off sc0 sc1\n\ts_waitcnt vmcnt(0)"
               : "=&v"(r) : "v"(p) : "memory");
  return r;
}
DEV void stg16_ic(void* p, u32x4 v){
  asm volatile("global_store_dwordx4 %0, %1, off sc0 sc1" :: "v"(p), "v"(v) : "memory");
}
DEV void stg16_l2(void* p, u32x4 v){
  asm volatile("global_store_dwordx4 %0, %1, off sc0" :: "v"(p), "v"(v) : "memory");
}
DEV void stf_sc(float* p, float v){
  asm volatile("global_store_dword %0, %1, off sc0 sc1" :: "v"(p), "v"(v) : "memory");
}
DEV unsigned ld_spin_ic(const unsigned* p){
  unsigned r;
  asm volatile("global_load_dword %0, %1, off sc0 sc1\n\ts_waitcnt vmcnt(0)"
               : "=&v"(r) : "v"(p) : "memory");
  return r;
}

template<bool L2H> DEV void ldg16h(u32x4 r[16], const void* b0, const void* b1){
  if constexpr (L2H) ldg16_l2(r, b0, b1); else ldg16_ic(r, b0, b1);
}
template<bool L2H> DEV void stg16h(void* p, u32x4 v){
  if constexpr (L2H) stg16_l2(p, v); else stg16_ic(p, v);
}

// ------------------------------------------------------------------
// Args
// ------------------------------------------------------------------
struct PArgs {
  const u16 *whh0[3], *wih0p[3], *whh1[3], *wih1[3];
  const float *b0[3], *b1[3];
  const float *x[3];
  const u16 *winH; const float *winLev;
  const u16 *gT;
  const float *gb, *wout, *adj, *fstd;
  u16 *h0a, *h0b, *h1a, *h1b;     // h state (L2 path when site is XCD-uniform)
  u16 *hgA, *hgB;                 // hinG bf16 (always IC: cross-site readers)
  float *levA, *levB;             // lev (always IC)
  float *out;
  unsigned *bar;   // cA[s][bt]=(s*2+bt)*64 ; cB[s][bt]=1024+(s*2+bt)*64
                   // detectCnt=2048 ; siteXcdMask[s]=2112+s*64
  int T[3]; int IN[3];
};

// ------------------------------------------------------------------
// LDS weight pinning (R6-proven). Row n at n*512B, slot ks at ks^(n&7).
// ------------------------------------------------------------------
DEV void pinW256(const u16* Wsite, int gt, u16* lds, int tid){
#pragma unroll
  for (int it = 0; it < 8; ++it){
    int flat = it*512 + tid;
    int n = flat >> 5, ks = flat & 31;
    int j = (n >> 5)*256 + gt*32 + (n & 31);
    bf16x8 v = *reinterpret_cast<const bf16x8*>(Wsite + (size_t)j*256 + ks*8);
    int sl = ks ^ (n & 7);
    *reinterpret_cast<bf16x8*>(lds + n*256 + sl*8) = v;
  }
}
DEV void pinWp(const u16* wpSite, int gt, u16* lds, int tid){
  int n = tid >> 2, ks = tid & 3;
  int j = (n >> 5)*256 + gt*32 + (n & 31);
  bf16x8 v = *reinterpret_cast<const bf16x8*>(wpSite + (size_t)j*32 + ks*8);
  int sl = ks ^ (n & 3);
  *reinterpret_cast<bf16x8*>(lds + n*32 + sl*8) = v;
}
DEV void pinWin(const u16* winH, int s, int gt, u16* lds, int tid){
#pragma unroll
  for (int it = 0; it < 2; ++it){
    int flat = it*512 + tid;
    int nn = flat >> 5, ks = flat & 31;
    bf16x8 v = *reinterpret_cast<const bf16x8*>(winH + ((size_t)s*256 + gt*32 + nn)*256 + ks*8);
    int sl = ks ^ (nn & 7);
    *reinterpret_cast<bf16x8*>(lds + nn*256 + sl*8) = v;
  }
}

// ------------------------------------------------------------------
// Wave GEMM segment (R6). Wave tile: M=32 (2 mf) x N=64 (4 gates x 16 hc).
// ------------------------------------------------------------------
DEV void seg_mfma(const u16* ldsW, const u32x4 a[16], f32x4 acc[2][4],
                  int l15, int l4, int nh){
#pragma unroll
  for (int ck = 0; ck < 8; ++ck){
#pragma unroll
    for (int mf = 0; mf < 2; ++mf){
      FragU af; af.q = a[mf*8 + ck];
#pragma unroll
      for (int q = 0; q < 4; ++q){
        int n = q*32 + nh*16 + l15;
        int sl = (ck*4 + l4) ^ (n & 7);
        acc[mf][q] = __builtin_amdgcn_mfma_f32_16x16x32_bf16(
            af.v, *reinterpret_cast<const bf16x8*>(ldsW + n*256 + sl*8), acc[mf][q], 0,0,0);
      }
    }
  }
}

template<bool L2H>
DEV void cell_epi2(const float bb[4], float* cR, u16* hOutSite,
                   int rowBase, int hcb, int lane, u16* wscr, const f32x4 acc[2][4]){
  int l15 = lane & 15, l4 = lane >> 4;
#pragma unroll
  for (int mf = 0; mf < 2; ++mf)
#pragma unroll
    for (int r = 0; r < 4; ++r){
      float gi = acc[mf][0][r] + bb[0];
      float gf = acc[mf][1][r] + bb[1];
      float gg = acc[mf][2][r] + bb[2];
      float go = acc[mf][3][r] + bb[3];
      float cn = sigf(gf)*cR[mf*4+r] + sigf(gi)*tanhf_(gg);
      cR[mf*4+r] = cn;
      wscr[(mf*16 + l4*4 + r)*16 + l15] = f2bf(sigf(go)*tanhf_(cn));
    }
  asm volatile("s_waitcnt lgkmcnt(0)" ::: "memory");
  u32x4 v = *reinterpret_cast<const u32x4*>(wscr + lane*8);
  stg16h<L2H>(hOutSite + (size_t)(rowBase + (lane>>1))*256 + hcb + (lane&1)*8, v);
}

// ------------------------------------------------------------------
// Main loop (R8 body + R8 slack-1 sync, h-transport templated).
// famA (fam=0): L0 cell + hinG ; famB: L1 cell + graph.
// Skew: L0(ss), L1(ss-1), hinG(ss-2), graph(ss-3).
// ------------------------------------------------------------------
template<bool L2H>
DEV void mainLoop(const PArgs& A, char* smem, int bid, int tid){
  u16* lds0 = (u16*)smem;                           // 64KB: Whh0 | Whh1
  u16* lds1 = (u16*)(smem + 65536);                 // famA: wp 8KB ; famB: Wih1 64KB
  u16* ldsWin = (u16*)(smem + 65536 + 8192);        // famA: winH tile 16KB
  u16* scratch = (u16*)(smem + 131072);             // 8KB bounce (1KB/wave)
  float (*red)[16] = (float(*)[16])(smem + 139264); // 512B
  __shared__ unsigned pollE[8], pollD[8];

  const int w = tid >> 6, lane = tid & 63, l15 = lane & 15, l4 = lane >> 4;
  const int s = bid & 7, fam = (bid >> 3) & 1, sub = bid >> 4;
  const int bt = sub & 1, gt = sub >> 1;
  const int mt = w & 3, nh = w >> 2;
  const int rowBase = bt*128 + mt*32;
  const int hcb = gt*32 + nh*16;
  const size_t sOff = (size_t)s*65536;
  u16* wscr = scratch + w*512;

  auto offA = [](int ss, int bb){ return (unsigned)((ss*2 + bb)*64); };
  auto offB = [](int ss, int bb){ return (unsigned)(1024 + (ss*2 + bb)*64); };
  if (tid == 0){
    pollE[0] = offA(s, bt); pollE[1] = offB(s, bt);
#pragma unroll
    for (int i = 2; i < 8; ++i) pollE[i] = pollE[0];
    if (fam == 0){
      pollD[0] = offA(s, bt);
      pollD[1] = offB(s, 0); pollD[2] = offB(s, 1);
      pollD[3] = (s > 0) ? offB(s-1, 0) : pollD[0];
      pollD[4] = (s > 0) ? offB(s-1, 1) : pollD[0];
      pollD[5] = pollD[0]; pollD[6] = pollD[0]; pollD[7] = pollD[0];
    } else {
      pollD[0] = offA(s, 0); pollD[1] = offA(s, 1);
      pollD[2] = offB(s, 0); pollD[3] = offB(s, 1);
      if (s < 7){
        pollD[4] = offA(s+1, 0); pollD[5] = offA(s+1, 1);
        pollD[6] = offB(s+1, 0); pollD[7] = offB(s+1, 1);
      } else {
        pollD[4] = pollD[0]; pollD[5] = pollD[0];
        pollD[6] = pollD[0]; pollD[7] = pollD[0];
      }
    }
  }
  unsigned* myCnt = A.bar + ((fam == 0) ? offA(s, bt) : offB(s, bt));
  __syncthreads();

  float cR[8];
#pragma unroll
  for (int i = 0; i < 8; ++i) cR[i] = 0.f;

  unsigned gen = 0;
  const int gb0[3] = {0, 90, 104};

  for (int ph = 0; ph < 3; ++ph){
    const int T = A.T[ph];
    const int IN = A.IN[ph];
    const bool dec = (ph > 0);
    const int SS = T + (dec ? 3 : 1);
    const int tdb = (ph == 2) ? 14 : 0;

    float bb[4];
    if (fam == 0){
      pinW256(A.whh0[ph] + (size_t)s*262144, gt, lds0, tid);
      pinWp  (A.wih0p[ph] + (size_t)s*32768, gt, lds1, tid);
      pinWin (A.winH, s, gt, ldsWin, tid);
      const float* bS = A.b0[ph] + s*1024;
#pragma unroll
      for (int g = 0; g < 4; ++g) bb[g] = bS[g*256 + hcb + l15];
    } else {
      pinW256(A.whh1[ph] + (size_t)s*262144, gt, lds0, tid);
      pinW256(A.wih1[ph] + (size_t)s*262144, gt, lds1, tid);
      const float* bS = A.b1[ph] + s*1024;
#pragma unroll
      for (int g = 0; g < 4; ++g) bb[g] = bS[g*256 + hcb + l15];
    }
    __syncthreads();

    for (int ss = 0; ss < SS; ++ss){
      // ---- POLL (IC counters, R8-proven) ----
      if (w == 0){
        unsigned off = (dec ? pollD : pollE)[lane & 7];
        const unsigned* p = A.bar + off;
        unsigned tgt = 8u * gen;
        for (;;){
          unsigned v = ld_spin_ic(p);
          if (__all((int)(v >= tgt))) break;
          __builtin_amdgcn_s_sleep(1);
        }
      }
      __syncthreads();

      if (fam == 0){
        // ---- L0(t=ss) ----
        if (ss < T){
          int t = ss, g0 = gb0[ph] + t;
          const u16* h0in = ((g0 & 1) ? A.h0b : A.h0a) + sOff;
          u16* h0out = ((g0 & 1) ? A.h0a : A.h0b) + sOff;
          f32x4 acc[2][4];
#pragma unroll
          for (int mf = 0; mf < 2; ++mf)
#pragma unroll
            for (int q = 0; q < 4; ++q) acc[mf][q] = (f32x4){0.f,0.f,0.f,0.f};
          u32x4 a[16];
          ldg16h<L2H>(a, h0in + (size_t)(rowBase + l15)*256 + l4*8,
                         h0in + (size_t)(rowBase + 16 + l15)*256 + l4*8);
          FragU xa[2];
#pragma unroll
          for (int mf = 0; mf < 2; ++mf){
#pragma unroll
            for (int e = 0; e < 8; ++e) xa[mf].u[e] = 0;
            const float* xrow = A.x[ph] + ((size_t)(s*256 + rowBase + mf*16 + l15)*T + t)*IN;
            if (IN == 16){
              if (l4 < 2){
                float4 u0 = reinterpret_cast<const float4*>(xrow)[l4*2];
                float4 u1 = reinterpret_cast<const float4*>(xrow)[l4*2+1];
                xa[mf].u[0]=f2bf(u0.x); xa[mf].u[1]=f2bf(u0.y); xa[mf].u[2]=f2bf(u0.z); xa[mf].u[3]=f2bf(u0.w);
                xa[mf].u[4]=f2bf(u1.x); xa[mf].u[5]=f2bf(u1.y); xa[mf].u[6]=f2bf(u1.z); xa[mf].u[7]=f2bf(u1.w);
              }
            } else {
              if (l4 == 0){
                float4 u0 = *reinterpret_cast<const float4*>(xrow);
                xa[mf].u[0]=f2bf(u0.x); xa[mf].u[1]=f2bf(u0.y); xa[mf].u[2]=f2bf(u0.z); xa[mf].u[3]=f2bf(u0.w);
              }
            }
          }
          wait_vm0();
          seg_mfma(lds0, a, acc, l15, l4, nh);
#pragma unroll
          for (int mf = 0; mf < 2; ++mf)
#pragma unroll
            for (int q = 0; q < 4; ++q){
              int n = q*32 + nh*16 + l15;
              int sl = l4 ^ (n & 3);
              acc[mf][q] = __builtin_amdgcn_mfma_f32_16x16x32_bf16(
                  xa[mf].v, *reinterpret_cast<const bf16x8*>(lds1 + n*32 + sl*8), acc[mf][q], 0,0,0);
            }
          cell_epi2<L2H>(bb, cR, h0out, rowBase, hcb, lane, wscr, acc);
        }
        // ---- hinG(t=ss-2): bf16 out, IC store (cross-site readers) ----
        if (dec){
          int th = ss - 2;
          if (th >= 0 && th < T){
            int g = gb0[ph] + th, tdec = tdb + th;
            const u16* h1cur = ((g & 1) ? A.h1a : A.h1b) + sOff;
            u16* hg = ((tdec & 1) ? A.hgB : A.hgA) + sOff;
            f32x4 a2[2];
            a2[0] = (f32x4){0.f,0.f,0.f,0.f}; a2[1] = a2[0];
            u32x4 a[16];
            ldg16h<L2H>(a, h1cur + (size_t)(rowBase + l15)*256 + l4*8,
                           h1cur + (size_t)(rowBase + 16 + l15)*256 + l4*8);
            wait_vm0();
#pragma unroll
            for (int ck = 0; ck < 8; ++ck)
#pragma unroll
              for (int mf = 0; mf < 2; ++mf){
                FragU af; af.q = a[mf*8 + ck];
                int n = nh*16 + l15;
                int sl = (ck*4 + l4) ^ (n & 7);
                a2[mf] = __builtin_amdgcn_mfma_f32_16x16x32_bf16(
                    af.v, *reinterpret_cast<const bf16x8*>(ldsWin + n*256 + sl*8), a2[mf], 0,0,0);
              }
#pragma unroll
            for (int mf = 0; mf < 2; ++mf)
#pragma unroll
              for (int r = 0; r < 4; ++r)
                wscr[(mf*16 + l4*4 + r)*16 + l15] = f2bf(a2[mf][r]);
            asm volatile("s_waitcnt lgkmcnt(0)" ::: "memory");
            u32x4 v = *reinterpret_cast<const u32x4*>(wscr + lane*8);
            stg16_ic(hg + (size_t)(rowBase + (lane>>1))*256 + hcb + (lane&1)*8, v);
          }
        }
      } else {
        // ---- L1(t=ss-1) ----
        int t = ss - 1;
        if (t >= 0 && t < T){
          int g = gb0[ph] + t;
          const u16* h1in = ((g & 1) ? A.h1b : A.h1a) + sOff;
          u16* h1out = ((g & 1) ? A.h1a : A.h1b) + sOff;
          const u16* h0cur = ((g & 1) ? A.h0a : A.h0b) + sOff;
          f32x4 acc[2][4];
#pragma unroll
          for (int mf = 0; mf < 2; ++mf)
#pragma unroll
            for (int q = 0; q < 4; ++q) acc[mf][q] = (f32x4){0.f,0.f,0.f,0.f};
          u32x4 a0[16], a1[16];
          ldg16h<L2H>(a0, h1in + (size_t)(rowBase + l15)*256 + l4*8,
                          h1in + (size_t)(rowBase + 16 + l15)*256 + l4*8);
          ldg16h<L2H>(a1, h0cur + (size_t)(rowBase + l15)*256 + l4*8,
                          h0cur + (size_t)(rowBase + 16 + l15)*256 + l4*8);
          wait_vm16();
          seg_mfma(lds0, a0, acc, l15, l4, nh);
          wait_vm0();
          seg_mfma(lds1, a1, acc, l15, l4, nh);
          cell_epi2<L2H>(bb, cR, h1out, rowBase, hcb, lane, wscr, acc);
        }
        // ---- graph(t=ss-3): all IC (cross-site) ----
        if (dec){
          int tgl = ss - 3;
          if (tgl >= 0 && tgl < T){
            int tg = tdb + tgl;
            const u16* hgb16 = (tg & 1) ? A.hgB : A.hgA;
            const float* levc = (tg & 1) ? A.levB : A.levA;
            float* levn = (tg & 1) ? A.levA : A.levB;
            int brow0 = sub*16;
            f32x4 acc[2];
            acc[0] = (f32x4){0.f,0.f,0.f,0.f}; acc[1] = acc[0];
            for (int ts = 0; ts < 8; ++ts){
              float av = A.adj[s*8 + ts];
              if (av == 0.f) continue;
              float lv;
              u32x4 hv[8];
              ldg8f_sc(hv, lv, hgb16 + (size_t)ts*65536 + (size_t)(brow0 + l15)*256 + l4*8,
                       levc + ts*256 + brow0 + l15);
              const float* wlB = A.winLev + ts*256 + l4*8;
#pragma unroll
              for (int ck = 0; ck < 8; ++ck){
                FragU hr; hr.q = hv[ck];
                float4 w0 = *reinterpret_cast<const float4*>(wlB + ck*32);
                float4 w1 = *reinterpret_cast<const float4*>(wlB + ck*32 + 4);
                float wls[8] = {w0.x,w0.y,w0.z,w0.w,w1.x,w1.y,w1.z,w1.w};
                FragU af;
#pragma unroll
                for (int e = 0; e < 8; ++e)
                  af.u[e] = f2bf(fmaxf(bf2f(hr.u[e]) + lv*wls[e], 0.f) * av);
#pragma unroll
                for (int q = 0; q < 2; ++q){
                  int n = (w*2+q)*16 + l15;
                  bf16x8 bfr = *reinterpret_cast<const bf16x8*>(A.gT + (size_t)n*256 + ck*32 + l4*8);
                  acc[q] = __builtin_amdgcn_mfma_f32_16x16x32_bf16(af.v, bfr, acc[q], 0,0,0);
                }
              }
            }
            float part[4] = {0.f,0.f,0.f,0.f};
            const float* woS = A.wout + s*256;
#pragma unroll
            for (int q = 0; q < 2; ++q){
              int m = (w*2+q)*16 + l15;
              float gbv = A.gb[m], wo = woS[m];
#pragma unroll
              for (int r = 0; r < 4; ++r) part[r] += fmaxf(acc[q][r] + gbv, 0.f) * wo;
            }
#pragma unroll
            for (int d = 1; d < 16; d <<= 1)
#pragma unroll
              for (int r = 0; r < 4; ++r) part[r] += __shfl_xor(part[r], d, 64);
            if (l15 == 0)
#pragma unroll
              for (int r = 0; r < 4; ++r) red[w][l4*4+r] = part[r];
            __syncthreads();
            if (tid < 16){
              float flow = 0.f;
#pragma unroll
              for (int ww = 0; ww < 8; ++ww) flow += red[ww][tid];
              int b = brow0 + tid;
              A.out[(size_t)b*720 + tg*8 + s] = flow;
              float lvo = ldf_sc(levc + s*256 + b);
              stf_sc(levn + s*256 + b, lvo + flow * A.fstd[s]);
            }
          }
        }
      }
      // ---- DRAIN + SIGNAL (IC counter, R8-proven) ----
      asm volatile("s_waitcnt vmcnt(0)" ::: "memory");
      __syncthreads();
      if (tid == 0) __hip_atomic_fetch_add(myCnt, 1u, RLX, AGT);
      ++gen;
    }
  }
}

__global__ __launch_bounds__(512, 2) void k_persist(PArgs A){
  extern __shared__ char smem[];
  __shared__ unsigned shFlag;
  const int bid = blockIdx.x, tid = threadIdx.x;
  const int s = bid & 7;
  // --- one-shot XCD-uniformity detection per site (monotonic counter,
  //     deadlock-free; data-path-only decision, sync protocol unaffected) ---
  unsigned xcd = 0;
  asm volatile("s_getreg_b32 %0, hwreg(HW_REG_XCC_ID)" : "=s"(xcd));
  if (tid == 0){
    __hip_atomic_fetch_or(A.bar + 2112 + s*64, 1u << (xcd & 31), RLX, AGT);
    __hip_atomic_fetch_add(A.bar + 2048, 1u, RLX, AGT);
    while (__hip_atomic_load(A.bar + 2048, RLX, AGT) < 256u) __builtin_amdgcn_s_sleep(2);
    unsigned m = __hip_atomic_load(A.bar + 2112 + s*64, RLX, AGT);
    shFlag = (__popc(m) == 1) ? 1u : 0u;
  }
  __syncthreads();
  if (shFlag) mainLoop<true>(A, smem, bid, tid);
  else        mainLoop<false>(A, smem, bid, tid);
}

// ------------------------------------------------------------------
// Preamble conversion kernels
// ------------------------------------------------------------------
struct Cvt9Args { const float* s[9]; u16* d[9]; };
__global__ void k_cvt9(Cvt9Args A){
  size_t i = (size_t)blockIdx.x*256 + threadIdx.x;
  int t = (int)(i >> 21); size_t r = i & 2097151u;
  A.d[t][r] = f2bf(A.s[t][r]);
}
struct Pad3Args { const float* s[3]; u16* d[3]; int kx[3]; };
__global__ void k_pad3(Pad3Args A){
  size_t i = (size_t)blockIdx.x*256 + threadIdx.x;
  int t = (int)(i >> 18); int r = (int)(i & 262143u);
  int row = r >> 5, col = r & 31;
  int kx = A.kx[t];
  A.d[t][r] = (col < kx) ? f2bf(A.s[t][(size_t)row*kx + col]) : (u16)0;
}
__global__ void k_win(const float* win, u16* winH, float* winLev){
  size_t i = (size_t)blockIdx.x*256 + threadIdx.x;
  if (i >= (size_t)8*256*257) return;
  int k = (int)(i % 257); size_t sm = i / 257;
  float v = win[i];
  if (k < 256) winH[sm*256 + k] = f2bf(v);
  else winLev[sm] = v;
}
__global__ void k_gt(const float* gW, u16* gT){
  int i = blockIdx.x*256 + threadIdx.x;
  int h = i >> 8, k = i & 255;
  gT[(size_t)k*256 + h] = f2bf(gW[i]);
}

// ------------------------------------------------------------------
// Host
// ------------------------------------------------------------------
extern "C" void kernel_launch(void* const* d_in, const int* in_sizes, int n_in,
                              void* d_out, int out_size, void* d_ws, size_t ws_size,
                              hipStream_t stream){
  const float* x_d    = (const float*)d_in[0];
  const float* x_f    = (const float*)d_in[1];
  const float* x_ff   = (const float*)d_in[2];
  const float* level0 = (const float*)d_in[3];
  const float* fstd   = (const float*)d_in[4];
  const float* adj    = (const float*)d_in[5];
  const float* W[18];
  for (int i = 0; i < 18; i++) W[i] = (const float*)d_in[6+i];
  const float* win  = (const float*)d_in[24];
  const float* wout = (const float*)d_in[25];
  const float* gW   = (const float*)d_in[26];
  const float* gb   = (const float*)d_in[27];

  char* base = (char*)d_ws;
  size_t off = 0;
  auto alloc = [&](size_t bytes)->void*{
    void* r = base + off;
    off += (bytes + 255) & ~(size_t)255;
    return r;
  };
  u16* wb[9]; for (int i = 0; i < 9; i++) wb[i] = (u16*)alloc((size_t)2097152*2);
  u16* wp[3]; for (int i = 0; i < 3; i++) wp[i] = (u16*)alloc((size_t)262144*2);
  u16* winH = (u16*)alloc((size_t)524288*2);
  u16* gT   = (u16*)alloc((size_t)65536*2);
  float* winLev = (float*)alloc((size_t)2048*4);
  u16* h0a = (u16*)alloc((size_t)524288*2);
  u16* h0b = (u16*)alloc((size_t)524288*2);
  u16* h1a = (u16*)alloc((size_t)524288*2);
  u16* h1b = (u16*)alloc((size_t)524288*2);
  u16* hgA = (u16*)alloc((size_t)524288*2);
  u16* hgB = (u16*)alloc((size_t)524288*2);
  float* levA = (float*)alloc((size_t)2048*4);
  float* levB = (float*)alloc((size_t)2048*4);
  unsigned* bar = (unsigned*)alloc(16384);

  Cvt9Args c9;
  const float* c9s[9] = { W[1], W[4], W[3],  W[7], W[10], W[9],  W[13], W[16], W[15] };
  for (int i = 0; i < 9; i++){ c9.s[i] = c9s[i]; c9.d[i] = wb[i]; }
  k_cvt9<<<73728,256,0,stream>>>(c9);

  Pad3Args p3;
  const float* p3s[3] = { W[0], W[6], W[12] };
  int kx3[3] = {16,16,4};
  for (int i = 0; i < 3; i++){ p3.s[i] = p3s[i]; p3.d[i] = wp[i]; p3.kx[i] = kx3[i]; }
  k_pad3<<<3072,256,0,stream>>>(p3);

  k_win<<<2057,256,0,stream>>>(win, winH, winLev);
  k_gt<<<256,256,0,stream>>>(gW, gT);

  (void)hipMemsetAsync(h0a, 0, (size_t)524288*2, stream);
  (void)hipMemsetAsync(h1a, 0, (size_t)524288*2, stream);
  (void)hipMemsetAsync(bar, 0, 16384, stream);
  (void)hipMemcpyAsync(levA, level0, (size_t)2048*4, hipMemcpyDeviceToDevice, stream);

  PArgs A;
  for (int ph = 0; ph < 3; ++ph){
    A.whh0[ph] = wb[ph*3+0];
    A.whh1[ph] = wb[ph*3+1];
    A.wih1[ph] = wb[ph*3+2];
    A.wih0p[ph] = wp[ph];
  }
  A.b0[0] = W[2];  A.b1[0] = W[5];
  A.b0[1] = W[8];  A.b1[1] = W[11];
  A.b0[2] = W[14]; A.b1[2] = W[17];
  A.x[0] = x_d; A.x[1] = x_f; A.x[2] = x_ff;
  A.winH = winH; A.winLev = winLev;
  A.gT = gT; A.gb = gb; A.wout = wout; A.adj = adj; A.fstd = fstd;
  A.h0a = h0a; A.h0b = h0b; A.h1a = h1a; A.h1b = h1b;
  A.hgA = hgA; A.hgB = hgB;
  A.levA = levA; A.levB = levB;
  A.out = (float*)d_out;
  A.bar = bar;
  A.T[0] = 90; A.T[1] = 14; A.T[2] = 76;
  A.IN[0] = 16; A.IN[1] = 16; A.IN[2] = 4;

  const int smemBytes = 139776;
  (void)hipFuncSetAttribute((const void*)k_persist, hipFuncAttributeMaxDynamicSharedMemorySize, smemBytes);
  k_persist<<<dim3(256), dim3(512), smemBytes, stream>>>(A);
}

// Round 10
// 2864.169 us; speedup vs baseline: 1.5071x; 1.5071x over previous
//
#include <hip/hip_runtime.h>

typedef unsigned short u16;
typedef __bf16 bf16_t;
typedef bf16_t bf16x8 __attribute__((ext_vector_type(8)));
typedef float f32x4 __attribute__((ext_vector_type(4)));
typedef unsigned int u32x4 __attribute__((ext_vector_type(4)));

#define DEV static __device__ __forceinline__
#define RLX __ATOMIC_RELAXED
#define AGT __HIP_MEMORY_SCOPE_AGENT

DEV u16 f2bf(float f){ unsigned u = __float_as_uint(f); return (u16)((u + 0x7fffu + ((u>>16)&1u))>>16); }
DEV float bf2f(u16 b){ return __uint_as_float(((unsigned)b)<<16); }
DEV float sigf(float x){ return 1.0f/(1.0f+__expf(-x)); }
DEV float tanhf_(float x){ float e = __expf(2.0f*x); return 1.0f - 2.0f/(e+1.0f); }

union FragU { bf16x8 v; u16 u[8]; u32x4 q; };

// ------------------------------------------------------------------
// IC-coherent (cross-XCD safe) memory ops: sc0 sc1 bypass L1+L2.
// (R8-proven transport: IC serves the hot-line broadcast ~10x better
// than a single XCD L2 — R9 measured.) Loads issue-only; pair with wait_vm*.
// ------------------------------------------------------------------
DEV void ldg8_nw(u32x4 r[8], const void* b0){
  asm volatile(
    "global_load_dwordx4 %0, %8, off sc0 sc1\n\t"
    "global_load_dwordx4 %1, %8, off offset:64 sc0 sc1\n\t"
    "global_load_dwordx4 %2, %8, off offset:128 sc0 sc1\n\t"
    "global_load_dwordx4 %3, %8, off offset:192 sc0 sc1\n\t"
    "global_load_dwordx4 %4, %8, off offset:256 sc0 sc1\n\t"
    "global_load_dwordx4 %5, %8, off offset:320 sc0 sc1\n\t"
    "global_load_dwordx4 %6, %8, off offset:384 sc0 sc1\n\t"
    "global_load_dwordx4 %7, %8, off offset:448 sc0 sc1"
    : "=&v"(r[0]), "=&v"(r[1]), "=&v"(r[2]), "=&v"(r[3]),
      "=&v"(r[4]), "=&v"(r[5]), "=&v"(r[6]), "=&v"(r[7])
    : "v"(b0) : "memory");
}
DEV void wait_vm8(){ asm volatile("s_waitcnt vmcnt(8)" ::: "memory"); __builtin_amdgcn_sched_barrier(0); }
DEV void wait_vm0(){ asm volatile("s_waitcnt vmcnt(0)" ::: "memory"); __builtin_amdgcn_sched_barrier(0); }

DEV void ldg8f_sc(u32x4 r[8], float& lv, const void* b0, const float* lp){
  asm volatile(
    "global_load_dwordx4 %0, %9, off sc0 sc1\n\t"
    "global_load_dwordx4 %1, %9, off offset:64 sc0 sc1\n\t"
    "global_load_dwordx4 %2, %9, off offset:128 sc0 sc1\n\t"
    "global_load_dwordx4 %3, %9, off offset:192 sc0 sc1\n\t"
    "global_load_dwordx4 %4, %9, off offset:256 sc0 sc1\n\t"
    "global_load_dwordx4 %5, %9, off offset:320 sc0 sc1\n\t"
    "global_load_dwordx4 %6, %9, off offset:384 sc0 sc1\n\t"
    "global_load_dwordx4 %7, %9, off offset:448 sc0 sc1\n\t"
    "global_load_dword %8, %10, off sc0 sc1\n\t"
    "s_waitcnt vmcnt(0)"
    : "=&v"(r[0]), "=&v"(r[1]), "=&v"(r[2]), "=&v"(r[3]),
      "=&v"(r[4]), "=&v"(r[5]), "=&v"(r[6]), "=&v"(r[7]), "=&v"(lv)
    : "v"(b0), "v"(lp) : "memory");
}
DEV float ldf_sc(const float* p){
  float r;
  asm volatile("global_load_dword %0, %1, off sc0 sc1\n\ts_waitcnt vmcnt(0)"
               : "=&v"(r) : "v"(p) : "memory");
  return r;
}
DEV void stg16_sc(void* p, u32x4 v){
  asm volatile("global_store_dwordx4 %0, %1, off sc0 sc1" :: "v"(p), "v"(v) : "memory");
}
DEV void stf_sc(float* p, float v){
  asm volatile("global_store_dword %0, %1, off sc0 sc1" :: "v"(p), "v"(v) : "memory");
}
DEV unsigned ld_spin_ic(const unsigned* p){
  unsigned r;
  asm volatile("global_load_dword %0, %1, off sc0 sc1\n\ts_waitcnt vmcnt(0)"
               : "=&v"(r) : "v"(p) : "memory");
  return r;
}

// ------------------------------------------------------------------
// Args
// ------------------------------------------------------------------
struct PArgs {
  const u16 *whh0[3], *wih0p[3], *whh1[3], *wih1[3];
  const float *b0[3], *b1[3];
  const float *x[3];
  const u16 *winH; const float *winLev;
  const u16 *gT;
  const float *gb, *wout, *adj, *fstd;
  u16 *h0a, *h0b, *h1a, *h1b;
  u16 *hgA, *hgB;
  float *levA, *levB;
  float *out;
  unsigned *bar;   // cA[s][bt]=(s*2+bt)*64 ; cB[s][bt]=1024+(s*2+bt)*64
  int T[3]; int IN[3];
};

// ------------------------------------------------------------------
// LDS weight pinning (R6-proven). Row n at n*512B, slot ks at ks^(n&7).
// ------------------------------------------------------------------
DEV void pinW256(const u16* Wsite, int gt, u16* lds, int tid){
#pragma unroll
  for (int it = 0; it < 8; ++it){
    int flat = it*512 + tid;
    int n = flat >> 5, ks = flat & 31;
    int j = (n >> 5)*256 + gt*32 + (n & 31);
    bf16x8 v = *reinterpret_cast<const bf16x8*>(Wsite + (size_t)j*256 + ks*8);
    int sl = ks ^ (n & 7);
    *reinterpret_cast<bf16x8*>(lds + n*256 + sl*8) = v;
  }
}
DEV void pinWp(const u16* wpSite, int gt, u16* lds, int tid){
  int n = tid >> 2, ks = tid & 3;
  int j = (n >> 5)*256 + gt*32 + (n & 31);
  bf16x8 v = *reinterpret_cast<const bf16x8*>(wpSite + (size_t)j*32 + ks*8);
  int sl = ks ^ (n & 3);
  *reinterpret_cast<bf16x8*>(lds + n*32 + sl*8) = v;
}
DEV void pinWin(const u16* winH, int s, int gt, u16* lds, int tid){
#pragma unroll
  for (int it = 0; it < 2; ++it){
    int flat = it*512 + tid;
    int nn = flat >> 5, ks = flat & 31;
    bf16x8 v = *reinterpret_cast<const bf16x8*>(winH + ((size_t)s*256 + gt*32 + nn)*256 + ks*8);
    int sl = ks ^ (nn & 7);
    *reinterpret_cast<bf16x8*>(lds + nn*256 + sl*8) = v;
  }
}

// ------------------------------------------------------------------
// Wave GEMM segment, M16 x N128: wave owns 16 A-rows (no intra-block
// duplication of IC reads) and ALL 128 gate-cols. 8 B-frags per k-step:
// q = g*2 + h2 -> pinned row n = (q>>1)*32 + (q&1)*16 + l15.
// ------------------------------------------------------------------
DEV void seg_mfma8(const u16* ldsW, const u32x4 a[8], f32x4 acc[8], int l15, int l4){
#pragma unroll
  for (int ck = 0; ck < 8; ++ck){
    FragU af; af.q = a[ck];
#pragma unroll
    for (int q = 0; q < 8; ++q){
      int n = (q >> 1)*32 + (q & 1)*16 + l15;
      int sl = (ck*4 + l4) ^ (n & 7);
      acc[q] = __builtin_amdgcn_mfma_f32_16x16x32_bf16(
          af.v, *reinterpret_cast<const bf16x8*>(ldsW + n*256 + sl*8), acc[q], 0,0,0);
    }
  }
}

// LSTM pointwise + bf16 h-store via per-wave 1KB LDS transpose bounce.
// acc[q = g*2 + h2]; wave tile 16 rows x 32 hcols.
DEV void cell_epi(const float bb[4][2], float* cR, u16* hOutSite,
                  int rowBase, int hc0, int lane, u16* wscr, const f32x4 acc[8]){
  int l15 = lane & 15, l4 = lane >> 4;
#pragma unroll
  for (int h2 = 0; h2 < 2; ++h2)
#pragma unroll
    for (int r = 0; r < 4; ++r){
      float gi = acc[0 + h2][r] + bb[0][h2];
      float gf = acc[2 + h2][r] + bb[1][h2];
      float gg = acc[4 + h2][r] + bb[2][h2];
      float go = acc[6 + h2][r] + bb[3][h2];
      float cn = sigf(gf)*cR[h2*4+r] + sigf(gi)*tanhf_(gg);
      cR[h2*4+r] = cn;
      wscr[(l4*4 + r)*32 + h2*16 + l15] = f2bf(sigf(go)*tanhf_(cn));
    }
  asm volatile("s_waitcnt lgkmcnt(0)" ::: "memory");
  u32x4 v = *reinterpret_cast<const u32x4*>(wscr + (lane>>2)*32 + (lane&3)*8);
  stg16_sc(hOutSite + (size_t)(rowBase + (lane>>2))*256 + hc0 + (lane&3)*8, v);
}

// ------------------------------------------------------------------
// Persistent kernel. 256 blocks x 512 threads, 1 block/CU.
// famA (fam=0): L0 cell + hinG ; famB: L1 cell + graph.
// Skew: L0(ss), L1(ss-1), hinG(ss-2), graph(ss-3).
// Sync: R8-proven slack-1 producer-group IC counters.
// ------------------------------------------------------------------
__global__ __launch_bounds__(512, 2) void k_persist(PArgs A){
  extern __shared__ char smem[];
  u16* lds0 = (u16*)smem;                           // 64KB: Whh0 | Whh1
  u16* lds1 = (u16*)(smem + 65536);                 // famA: wp 8KB ; famB: Wih1 64KB
  u16* ldsWin = (u16*)(smem + 65536 + 8192);        // famA: winH tile 16KB
  u16* scratch = (u16*)(smem + 131072);             // 8KB bounce (1KB/wave)
  float (*red)[16] = (float(*)[16])(smem + 139264); // 512B
  __shared__ unsigned pollE[8], pollD[8];

  const int bid = blockIdx.x, tid = threadIdx.x;
  const int w = tid >> 6, lane = tid & 63, l15 = lane & 15, l4 = lane >> 4;
  const int s = bid & 7, fam = (bid >> 3) & 1, sub = bid >> 4;
  const int bt = sub & 1, gt = sub >> 1;
  const int rowBase = bt*128 + w*16;                // wave's 16 A-rows
  const int hc0 = gt*32;                            // block's hcol base
  const size_t sOff = (size_t)s*65536;
  u16* wscr = scratch + w*512;

  auto offA = [](int ss, int bb_){ return (unsigned)((ss*2 + bb_)*64); };
  auto offB = [](int ss, int bb_){ return (unsigned)(1024 + (ss*2 + bb_)*64); };
  if (tid == 0){
    pollE[0] = offA(s, bt); pollE[1] = offB(s, bt);
#pragma unroll
    for (int i = 2; i < 8; ++i) pollE[i] = pollE[0];
    if (fam == 0){
      pollD[0] = offA(s, bt);
      pollD[1] = offB(s, 0); pollD[2] = offB(s, 1);
      pollD[3] = (s > 0) ? offB(s-1, 0) : pollD[0];
      pollD[4] = (s > 0) ? offB(s-1, 1) : pollD[0];
      pollD[5] = pollD[0]; pollD[6] = pollD[0]; pollD[7] = pollD[0];
    } else {
      pollD[0] = offA(s, 0); pollD[1] = offA(s, 1);
      pollD[2] = offB(s, 0); pollD[3] = offB(s, 1);
      if (s < 7){
        pollD[4] = offA(s+1, 0); pollD[5] = offA(s+1, 1);
        pollD[6] = offB(s+1, 0); pollD[7] = offB(s+1, 1);
      } else {
        pollD[4] = pollD[0]; pollD[5] = pollD[0];
        pollD[6] = pollD[0]; pollD[7] = pollD[0];
      }
    }
  }
  unsigned* myCnt = A.bar + ((fam == 0) ? offA(s, bt) : offB(s, bt));
  __syncthreads();

  float cR[8];
#pragma unroll
  for (int i = 0; i < 8; ++i) cR[i] = 0.f;

  unsigned gen = 0;
  const int gb0[3] = {0, 90, 104};

  for (int ph = 0; ph < 3; ++ph){
    const int T = A.T[ph];
    const int IN = A.IN[ph];
    const bool dec = (ph > 0);
    const int SS = T + (dec ? 3 : 1);
    const int tdb = (ph == 2) ? 14 : 0;

    float bb[4][2];
    if (fam == 0){
      pinW256(A.whh0[ph] + (size_t)s*262144, gt, lds0, tid);
      pinWp  (A.wih0p[ph] + (size_t)s*32768, gt, lds1, tid);
      pinWin (A.winH, s, gt, ldsWin, tid);
      const float* bS = A.b0[ph] + s*1024;
#pragma unroll
      for (int g = 0; g < 4; ++g){ bb[g][0] = bS[g*256 + hc0 + l15]; bb[g][1] = bS[g*256 + hc0 + 16 + l15]; }
    } else {
      pinW256(A.whh1[ph] + (size_t)s*262144, gt, lds0, tid);
      pinW256(A.wih1[ph] + (size_t)s*262144, gt, lds1, tid);
      const float* bS = A.b1[ph] + s*1024;
#pragma unroll
      for (int g = 0; g < 4; ++g){ bb[g][0] = bS[g*256 + hc0 + l15]; bb[g][1] = bS[g*256 + hc0 + 16 + l15]; }
    }
    __syncthreads();

    for (int ss = 0; ss < SS; ++ss){
      // ---- POLL (IC counters, R8-proven) ----
      if (w == 0){
        unsigned off = (dec ? pollD : pollE)[lane & 7];
        const unsigned* p = A.bar + off;
        unsigned tgt = 8u * gen;
        for (;;){
          unsigned v = ld_spin_ic(p);
          if (__all((int)(v >= tgt))) break;
          __builtin_amdgcn_s_sleep(1);
        }
      }
      __syncthreads();

      if (fam == 0){
        // ---- L0(t=ss) ----
        if (ss < T){
          int t = ss, g0 = gb0[ph] + t;
          const u16* h0in = ((g0 & 1) ? A.h0b : A.h0a) + sOff;
          u16* h0out = ((g0 & 1) ? A.h0a : A.h0b) + sOff;
          f32x4 acc[8];
#pragma unroll
          for (int q = 0; q < 8; ++q) acc[q] = (f32x4){0.f,0.f,0.f,0.f};
          u32x4 a[8];
          ldg8_nw(a, h0in + (size_t)(rowBase + l15)*256 + l4*8);
          FragU xa;
#pragma unroll
          for (int e = 0; e < 8; ++e) xa.u[e] = 0;
          {
            const float* xrow = A.x[ph] + ((size_t)(s*256 + rowBase + l15)*T + t)*IN;
            if (IN == 16){
              if (l4 < 2){
                float4 u0 = reinterpret_cast<const float4*>(xrow)[l4*2];
                float4 u1 = reinterpret_cast<const float4*>(xrow)[l4*2+1];
                xa.u[0]=f2bf(u0.x); xa.u[1]=f2bf(u0.y); xa.u[2]=f2bf(u0.z); xa.u[3]=f2bf(u0.w);
                xa.u[4]=f2bf(u1.x); xa.u[5]=f2bf(u1.y); xa.u[6]=f2bf(u1.z); xa.u[7]=f2bf(u1.w);
              }
            } else {
              if (l4 == 0){
                float4 u0 = *reinterpret_cast<const float4*>(xrow);
                xa.u[0]=f2bf(u0.x); xa.u[1]=f2bf(u0.y); xa.u[2]=f2bf(u0.z); xa.u[3]=f2bf(u0.w);
              }
            }
          }
          wait_vm0();
          seg_mfma8(lds0, a, acc, l15, l4);
#pragma unroll
          for (int q = 0; q < 8; ++q){
            int n = (q >> 1)*32 + (q & 1)*16 + l15;
            int sl = l4 ^ (n & 3);
            acc[q] = __builtin_amdgcn_mfma_f32_16x16x32_bf16(
                xa.v, *reinterpret_cast<const bf16x8*>(lds1 + n*32 + sl*8), acc[q], 0,0,0);
          }
          cell_epi(bb, cR, h0out, rowBase, hc0, lane, wscr, acc);
        }
        // ---- hinG(t=ss-2): bf16 out (N=32 tile of winH) ----
        if (dec){
          int th = ss - 2;
          if (th >= 0 && th < T){
            int g = gb0[ph] + th, tdec = tdb + th;
            const u16* h1cur = ((g & 1) ? A.h1a : A.h1b) + sOff;
            u16* hg = ((tdec & 1) ? A.hgB : A.hgA) + sOff;
            f32x4 a2[2];
            a2[0] = (f32x4){0.f,0.f,0.f,0.f}; a2[1] = a2[0];
            u32x4 a[8];
            ldg8_nw(a, h1cur + (size_t)(rowBase + l15)*256 + l4*8);
            wait_vm0();
#pragma unroll
            for (int ck = 0; ck < 8; ++ck){
              FragU af; af.q = a[ck];
#pragma unroll
              for (int q = 0; q < 2; ++q){
                int n = q*16 + l15;
                int sl = (ck*4 + l4) ^ (n & 7);
                a2[q] = __builtin_amdgcn_mfma_f32_16x16x32_bf16(
                    af.v, *reinterpret_cast<const bf16x8*>(ldsWin + n*256 + sl*8), a2[q], 0,0,0);
              }
            }
#pragma unroll
            for (int q = 0; q < 2; ++q)
#pragma unroll
              for (int r = 0; r < 4; ++r)
                wscr[(l4*4 + r)*32 + q*16 + l15] = f2bf(a2[q][r]);
            asm volatile("s_waitcnt lgkmcnt(0)" ::: "memory");
            u32x4 v = *reinterpret_cast<const u32x4*>(wscr + (lane>>2)*32 + (lane&3)*8);
            stg16_sc(hg + (size_t)(rowBase + (lane>>2))*256 + hc0 + (lane&3)*8, v);
          }
        }
      } else {
        // ---- L1(t=ss-1): both 8-load batches in flight, counted waits ----
        int t = ss - 1;
        if (t >= 0 && t < T){
          int g = gb0[ph] + t;
          const u16* h1in = ((g & 1) ? A.h1b : A.h1a) + sOff;
          u16* h1out = ((g & 1) ? A.h1a : A.h1b) + sOff;
          const u16* h0cur = ((g & 1) ? A.h0a : A.h0b) + sOff;
          f32x4 acc[8];
#pragma unroll
          for (int q = 0; q < 8; ++q) acc[q] = (f32x4){0.f,0.f,0.f,0.f};
          u32x4 a0[8], a1[8];
          ldg8_nw(a0, h1in + (size_t)(rowBase + l15)*256 + l4*8);
          ldg8_nw(a1, h0cur + (size_t)(rowBase + l15)*256 + l4*8);
          wait_vm8();
          seg_mfma8(lds0, a0, acc, l15, l4);
          wait_vm0();
          seg_mfma8(lds1, a1, acc, l15, l4);
          cell_epi(bb, cR, h1out, rowBase, hc0, lane, wscr, acc);
        }
        // ---- graph(t=ss-3) ----
        if (dec){
          int tgl = ss - 3;
          if (tgl >= 0 && tgl < T){
            int tg = tdb + tgl;
            const u16* hgb16 = (tg & 1) ? A.hgB : A.hgA;
            const float* levc = (tg & 1) ? A.levB : A.levA;
            float* levn = (tg & 1) ? A.levA : A.levB;
            int brow0 = sub*16;
            f32x4 acc[2];
            acc[0] = (f32x4){0.f,0.f,0.f,0.f}; acc[1] = acc[0];
            for (int ts = 0; ts < 8; ++ts){
              float av = A.adj[s*8 + ts];
              if (av == 0.f) continue;
              float lv;
              u32x4 hv[8];
              ldg8f_sc(hv, lv, hgb16 + (size_t)ts*65536 + (size_t)(brow0 + l15)*256 + l4*8,
                       levc + ts*256 + brow0 + l15);
              const float* wlB = A.winLev + ts*256 + l4*8;
#pragma unroll
              for (int ck = 0; ck < 8; ++ck){
                FragU hr; hr.q = hv[ck];
                float4 w0 = *reinterpret_cast<const float4*>(wlB + ck*32);
                float4 w1 = *reinterpret_cast<const float4*>(wlB + ck*32 + 4);
                float wls[8] = {w0.x,w0.y,w0.z,w0.w,w1.x,w1.y,w1.z,w1.w};
                FragU af;
#pragma unroll
                for (int e = 0; e < 8; ++e)
                  af.u[e] = f2bf(fmaxf(bf2f(hr.u[e]) + lv*wls[e], 0.f) * av);
#pragma unroll
                for (int q = 0; q < 2; ++q){
                  int n = (w*2+q)*16 + l15;
                  bf16x8 bfr = *reinterpret_cast<const bf16x8*>(A.gT + (size_t)n*256 + ck*32 + l4*8);
                  acc[q] = __builtin_amdgcn_mfma_f32_16x16x32_bf16(af.v, bfr, acc[q], 0,0,0);
                }
              }
            }
            float part[4] = {0.f,0.f,0.f,0.f};
            const float* woS = A.wout + s*256;
#pragma unroll
            for (int q = 0; q < 2; ++q){
              int m = (w*2+q)*16 + l15;
              float gbv = A.gb[m], wo = woS[m];
#pragma unroll
              for (int r = 0; r < 4; ++r) part[r] += fmaxf(acc[q][r] + gbv, 0.f) * wo;
            }
#pragma unroll
            for (int d = 1; d < 16; d <<= 1)
#pragma unroll
              for (int r = 0; r < 4; ++r) part[r] += __shfl_xor(part[r], d, 64);
            if (l15 == 0)
#pragma unroll
              for (int r = 0; r < 4; ++r) red[w][l4*4+r] = part[r];
            __syncthreads();
            if (tid < 16){
              float flow = 0.f;
#pragma unroll
              for (int ww = 0; ww < 8; ++ww) flow += red[ww][tid];
              int b = brow0 + tid;
              A.out[(size_t)b*720 + tg*8 + s] = flow;
              float lvo = ldf_sc(levc + s*256 + b);
              stf_sc(levn + s*256 + b, lvo + flow * A.fstd[s]);
            }
          }
        }
      }
      // ---- DRAIN + SIGNAL ----
      asm volatile("s_waitcnt vmcnt(0)" ::: "memory");
      __syncthreads();
      if (tid == 0) __hip_atomic_fetch_add(myCnt, 1u, RLX, AGT);
      ++gen;
    }
  }
}

// ------------------------------------------------------------------
// Preamble conversion kernels
// ------------------------------------------------------------------
struct Cvt9Args { const float* s[9]; u16* d[9]; };
__global__ void k_cvt9(Cvt9Args A){
  size_t i = (size_t)blockIdx.x*256 + threadIdx.x;
  int t = (int)(i >> 21); size_t r = i & 2097151u;
  A.d[t][r] = f2bf(A.s[t][r]);
}
struct Pad3Args { const float* s[3]; u16* d[3]; int kx[3]; };
__global__ void k_pad3(Pad3Args A){
  size_t i = (size_t)blockIdx.x*256 + threadIdx.x;
  int t = (int)(i >> 18); int r = (int)(i & 262143u);
  int row = r >> 5, col = r & 31;
  int kx = A.kx[t];
  A.d[t][r] = (col < kx) ? f2bf(A.s[t][(size_t)row*kx + col]) : (u16)0;
}
__global__ void k_win(const float* win, u16* winH, float* winLev){
  size_t i = (size_t)blockIdx.x*256 + threadIdx.x;
  if (i >= (size_t)8*256*257) return;
  int k = (int)(i % 257); size_t sm = i / 257;
  float v = win[i];
  if (k < 256) winH[sm*256 + k] = f2bf(v);
  else winLev[sm] = v;
}
__global__ void k_gt(const float* gW, u16* gT){
  int i = blockIdx.x*256 + threadIdx.x;
  int h = i >> 8, k = i & 255;
  gT[(size_t)k*256 + h] = f2bf(gW[i]);
}

// ------------------------------------------------------------------
// Host
// ------------------------------------------------------------------
extern "C" void kernel_launch(void* const* d_in, const int* in_sizes, int n_in,
                              void* d_out, int out_size, void* d_ws, size_t ws_size,
                              hipStream_t stream){
  const float* x_d    = (const float*)d_in[0];
  const float* x_f    = (const float*)d_in[1];
  const float* x_ff   = (const float*)d_in[2];
  const float* level0 = (const float*)d_in[3];
  const float* fstd   = (const float*)d_in[4];
  const float* adj    = (const float*)d_in[5];
  const float* W[18];
  for (int i = 0; i < 18; i++) W[i] = (const float*)d_in[6+i];
  const float* win  = (const float*)d_in[24];
  const float* wout = (const float*)d_in[25];
  const float* gW   = (const float*)d_in[26];
  const float* gb   = (const float*)d_in[27];

  char* base = (char*)d_ws;
  size_t off = 0;
  auto alloc = [&](size_t bytes)->void*{
    void* r = base + off;
    off += (bytes + 255) & ~(size_t)255;
    return r;
  };
  u16* wb[9]; for (int i = 0; i < 9; i++) wb[i] = (u16*)alloc((size_t)2097152*2);
  u16* wp[3]; for (int i = 0; i < 3; i++) wp[i] = (u16*)alloc((size_t)262144*2);
  u16* winH = (u16*)alloc((size_t)524288*2);
  u16* gT   = (u16*)alloc((size_t)65536*2);
  float* winLev = (float*)alloc((size_t)2048*4);
  u16* h0a = (u16*)alloc((size_t)524288*2);
  u16* h0b = (u16*)alloc((size_t)524288*2);
  u16* h1a = (u16*)alloc((size_t)524288*2);
  u16* h1b = (u16*)alloc((size_t)524288*2);
  u16* hgA = (u16*)alloc((size_t)524288*2);
  u16* hgB = (u16*)alloc((size_t)524288*2);
  float* levA = (float*)alloc((size_t)2048*4);
  float* levB = (float*)alloc((size_t)2048*4);
  unsigned* bar = (unsigned*)alloc(16384);

  Cvt9Args c9;
  const float* c9s[9] = { W[1], W[4], W[3],  W[7], W[10], W[9],  W[13], W[16], W[15] };
  for (int i = 0; i < 9; i++){ c9.s[i] = c9s[i]; c9.d[i] = wb[i]; }
  k_cvt9<<<73728,256,0,stream>>>(c9);

  Pad3Args p3;
  const float* p3s[3] = { W[0], W[6], W[12] };
  int kx3[3] = {16,16,4};
  for (int i = 0; i < 3; i++){ p3.s[i] = p3s[i]; p3.d[i] = wp[i]; p3.kx[i] = kx3[i]; }
  k_pad3<<<3072,256,0,stream>>>(p3);

  k_win<<<2057,256,0,stream>>>(win, winH, winLev);
  k_gt<<<256,256,0,stream>>>(gW, gT);

  (void)hipMemsetAsync(h0a, 0, (size_t)524288*2, stream);
  (void)hipMemsetAsync(h1a, 0, (size_t)524288*2, stream);
  (void)hipMemsetAsync(bar, 0, 16384, stream);
  (void)hipMemcpyAsync(levA, level0, (size_t)2048*4, hipMemcpyDeviceToDevice, stream);

  PArgs A;
  for (int ph = 0; ph < 3; ++ph){
    A.whh0[ph] = wb[ph*3+0];
    A.whh1[ph] = wb[ph*3+1];
    A.wih1[ph] = wb[ph*3+2];
    A.wih0p[ph] = wp[ph];
  }
  A.b0[0] = W[2];  A.b1[0] = W[5];
  A.b0[1] = W[8];  A.b1[1] = W[11];
  A.b0[2] = W[14]; A.b1[2] = W[17];
  A.x[0] = x_d; A.x[1] = x_f; A.x[2] = x_ff;
  A.winH = winH; A.winLev = winLev;
  A.gT = gT; A.gb = gb; A.wout = wout; A.adj = adj; A.fstd = fstd;
  A.h0a = h0a; A.h0b = h0b; A.h1a = h1a; A.h1b = h1b;
  A.hgA = hgA; A.hgB = hgB;
  A.levA = levA; A.levB = levB;
  A.out = (float*)d_out;
  A.bar = bar;
  A.T[0] = 90; A.T[1] = 14; A.T[2] = 76;
  A.IN[0] = 16; A.IN[1] = 16; A.IN[2] = 4;

  const int smemBytes = 139776;
  (void)hipFuncSetAttribute((const void*)k_persist, hipFuncAttributeMaxDynamicSharedMemorySize, smemBytes);
  k_persist<<<dim3(256), dim3(512), smemBytes, stream>>>(A);
}

// Round 15
// 2848.166 us; speedup vs baseline: 1.5156x; 1.0056x over previous
//
#include <hip/hip_runtime.h>

typedef unsigned short u16;
typedef __bf16 bf16_t;
typedef bf16_t bf16x8 __attribute__((ext_vector_type(8)));
typedef float f32x4 __attribute__((ext_vector_type(4)));
typedef unsigned int u32x4 __attribute__((ext_vector_type(4)));

#define DEV static __device__ __forceinline__
#define RLX __ATOMIC_RELAXED
#define AGT __HIP_MEMORY_SCOPE_AGENT

DEV u16 f2bf(float f){ unsigned u = __float_as_uint(f); return (u16)((u + 0x7fffu + ((u>>16)&1u))>>16); }
DEV float bf2f(u16 b){ return __uint_as_float(((unsigned)b)<<16); }
DEV float sigf(float x){ return 1.0f/(1.0f+__expf(-x)); }
DEV float tanhf_(float x){ float e = __expf(2.0f*x); return 1.0f - 2.0f/(e+1.0f); }

union FragU { bf16x8 v; u16 u[8]; u32x4 q; };

// ------------------------------------------------------------------
// IC-coherent (cross-XCD safe) memory ops: sc0 sc1 bypass L1+L2.
// R10-proven transport. Loads issue-only; pair with wait_vm*.
// ------------------------------------------------------------------
DEV void ldg8_nw(u32x4 r[8], const void* b0){
  asm volatile(
    "global_load_dwordx4 %0, %8, off sc0 sc1\n\t"
    "global_load_dwordx4 %1, %8, off offset:64 sc0 sc1\n\t"
    "global_load_dwordx4 %2, %8, off offset:128 sc0 sc1\n\t"
    "global_load_dwordx4 %3, %8, off offset:192 sc0 sc1\n\t"
    "global_load_dwordx4 %4, %8, off offset:256 sc0 sc1\n\t"
    "global_load_dwordx4 %5, %8, off offset:320 sc0 sc1\n\t"
    "global_load_dwordx4 %6, %8, off offset:384 sc0 sc1\n\t"
    "global_load_dwordx4 %7, %8, off offset:448 sc0 sc1"
    : "=&v"(r[0]), "=&v"(r[1]), "=&v"(r[2]), "=&v"(r[3]),
      "=&v"(r[4]), "=&v"(r[5]), "=&v"(r[6]), "=&v"(r[7])
    : "v"(b0) : "memory");
}
DEV void wait_vm8(){ asm volatile("s_waitcnt vmcnt(8)" ::: "memory"); __builtin_amdgcn_sched_barrier(0); }
DEV void wait_vm0(){ asm volatile("s_waitcnt vmcnt(0)" ::: "memory"); __builtin_amdgcn_sched_barrier(0); }

DEV void ldg8f_sc(u32x4 r[8], float& lv, const void* b0, const float* lp){
  asm volatile(
    "global_load_dwordx4 %0, %9, off sc0 sc1\n\t"
    "global_load_dwordx4 %1, %9, off offset:64 sc0 sc1\n\t"
    "global_load_dwordx4 %2, %9, off offset:128 sc0 sc1\n\t"
    "global_load_dwordx4 %3, %9, off offset:192 sc0 sc1\n\t"
    "global_load_dwordx4 %4, %9, off offset:256 sc0 sc1\n\t"
    "global_load_dwordx4 %5, %9, off offset:320 sc0 sc1\n\t"
    "global_load_dwordx4 %6, %9, off offset:384 sc0 sc1\n\t"
    "global_load_dwordx4 %7, %9, off offset:448 sc0 sc1\n\t"
    "global_load_dword %8, %10, off sc0 sc1\n\t"
    "s_waitcnt vmcnt(0)"
    : "=&v"(r[0]), "=&v"(r[1]), "=&v"(r[2]), "=&v"(r[3]),
      "=&v"(r[4]), "=&v"(r[5]), "=&v"(r[6]), "=&v"(r[7]), "=&v"(lv)
    : "v"(b0), "v"(lp) : "memory");
}
DEV float ldf_sc(const float* p){
  float r;
  asm volatile("global_load_dword %0, %1, off sc0 sc1\n\ts_waitcnt vmcnt(0)"
               : "=&v"(r) : "v"(p) : "memory");
  return r;
}
DEV void stg16_sc(void* p, u32x4 v){
  asm volatile("global_store_dwordx4 %0, %1, off sc0 sc1" :: "v"(p), "v"(v) : "memory");
}
DEV void stf_sc(float* p, float v){
  asm volatile("global_store_dword %0, %1, off sc0 sc1" :: "v"(p), "v"(v) : "memory");
}
DEV unsigned ld_spin_ic(const unsigned* p){
  unsigned r;
  asm volatile("global_load_dword %0, %1, off sc0 sc1\n\ts_waitcnt vmcnt(0)"
               : "=&v"(r) : "v"(p) : "memory");
  return r;
}

// ------------------------------------------------------------------
// Args
// ------------------------------------------------------------------
struct PArgs {
  const u16 *whh0[3], *wih0p[3], *whh1[3], *wih1[3];
  const float *b0[3], *b1[3];
  const float *x[3];
  const u16 *winH; const float *winLev;
  const u16 *gT;
  const float *gb, *wout, *adj, *fstd;
  u16 *h0a, *h0b, *h1a, *h1b;
  u16 *hgA, *hgB;
  float *levA, *levB;
  float *out;
  unsigned *bar;   // cA[s][bt]=(s*2+bt)*64 ; cB[s][bt]=1024+(s*2+bt)*64
  int T[3]; int IN[3];
};

// ------------------------------------------------------------------
// LDS weight pinning (R6-proven). Row n at n*512B, slot ks at ks^(n&7).
// ------------------------------------------------------------------
DEV void pinW256(const u16* Wsite, int gt, u16* lds, int tid){
#pragma unroll
  for (int it = 0; it < 8; ++it){
    int flat = it*512 + tid;
    int n = flat >> 5, ks = flat & 31;
    int j = (n >> 5)*256 + gt*32 + (n & 31);
    bf16x8 v = *reinterpret_cast<const bf16x8*>(Wsite + (size_t)j*256 + ks*8);
    int sl = ks ^ (n & 7);
    *reinterpret_cast<bf16x8*>(lds + n*256 + sl*8) = v;
  }
}
DEV void pinWp(const u16* wpSite, int gt, u16* lds, int tid){
  int n = tid >> 2, ks = tid & 3;
  int j = (n >> 5)*256 + gt*32 + (n & 31);
  bf16x8 v = *reinterpret_cast<const bf16x8*>(wpSite + (size_t)j*32 + ks*8);
  int sl = ks ^ (n & 3);
  *reinterpret_cast<bf16x8*>(lds + n*32 + sl*8) = v;
}
DEV void pinWin(const u16* winH, int s, int gt, u16* lds, int tid){
#pragma unroll
  for (int it = 0; it < 2; ++it){
    int flat = it*512 + tid;
    int nn = flat >> 5, ks = flat & 31;
    bf16x8 v = *reinterpret_cast<const bf16x8*>(winH + ((size_t)s*256 + gt*32 + nn)*256 + ks*8);
    int sl = ks ^ (nn & 7);
    *reinterpret_cast<bf16x8*>(lds + nn*256 + sl*8) = v;
  }
}

// ------------------------------------------------------------------
// Wave GEMM segment, M16 x N128: wave owns 16 A-rows (no intra-block
// duplication of IC reads) and ALL 128 gate-cols. 8 B-frags per k-step:
// q = g*2 + h2 -> pinned row n = (q>>1)*32 + (q&1)*16 + l15.
// ------------------------------------------------------------------
DEV void seg_mfma8(const u16* ldsW, const u32x4 a[8], f32x4 acc[8], int l15, int l4){
#pragma unroll
  for (int ck = 0; ck < 8; ++ck){
    FragU af; af.q = a[ck];
#pragma unroll
    for (int q = 0; q < 8; ++q){
      int n = (q >> 1)*32 + (q & 1)*16 + l15;
      int sl = (ck*4 + l4) ^ (n & 7);
      acc[q] = __builtin_amdgcn_mfma_f32_16x16x32_bf16(
          af.v, *reinterpret_cast<const bf16x8*>(ldsW + n*256 + sl*8), acc[q], 0,0,0);
    }
  }
}

// LSTM pointwise + bf16 h-store via per-wave 1KB LDS transpose bounce.
// acc[q = g*2 + h2]; wave tile 16 rows x 32 hcols.
DEV void cell_epi(const float bb[4][2], float* cR, u16* hOutSite,
                  int rowBase, int hc0, int lane, u16* wscr, const f32x4 acc[8]){
  int l15 = lane & 15, l4 = lane >> 4;
#pragma unroll
  for (int h2 = 0; h2 < 2; ++h2)
#pragma unroll
    for (int r = 0; r < 4; ++r){
      float gi = acc[0 + h2][r] + bb[0][h2];
      float gf = acc[2 + h2][r] + bb[1][h2];
      float gg = acc[4 + h2][r] + bb[2][h2];
      float go = acc[6 + h2][r] + bb[3][h2];
      float cn = sigf(gf)*cR[h2*4+r] + sigf(gi)*tanhf_(gg);
      cR[h2*4+r] = cn;
      wscr[(l4*4 + r)*32 + h2*16 + l15] = f2bf(sigf(go)*tanhf_(cn));
    }
  asm volatile("s_waitcnt lgkmcnt(0)" ::: "memory");
  u32x4 v = *reinterpret_cast<const u32x4*>(wscr + (lane>>2)*32 + (lane&3)*8);
  stg16_sc(hOutSite + (size_t)(rowBase + (lane>>2))*256 + hc0 + (lane&3)*8, v);
}

// ------------------------------------------------------------------
// Persistent kernel. 256 blocks x 512 threads, 1 block/CU (R10 layout,
// R10 transport, R10 load scheduling — the last fully-verified state).
// famA (fam=0): L0 cell + hinG ; famB: L1 cell + graph.
// Skew: L0(ss), L1(ss-1), hinG(ss-2), graph(ss-3).
// Sync: R8-proven slack-1 producer-group IC counters; the ONLY delta
// vs R10 is famB's poll also covering offB(s-1,*) (lev WAR closure) —
// strictly more conservative, cannot introduce races or hazards.
// ------------------------------------------------------------------
__global__ __launch_bounds__(512, 2) void k_persist(PArgs A){
  extern __shared__ char smem[];
  u16* lds0 = (u16*)smem;                           // 64KB: Whh0 | Whh1
  u16* lds1 = (u16*)(smem + 65536);                 // famA: wp 8KB ; famB: Wih1 64KB
  u16* ldsWin = (u16*)(smem + 65536 + 8192);        // famA: winH tile 16KB
  u16* scratch = (u16*)(smem + 131072);             // 8KB bounce (1KB/wave)
  float (*red)[16] = (float(*)[16])(smem + 139264); // 512B
  __shared__ unsigned pollE[16], pollD[16];

  const int bid = blockIdx.x, tid = threadIdx.x;
  const int w = tid >> 6, lane = tid & 63, l15 = lane & 15, l4 = lane >> 4;
  const int s = bid & 7, fam = (bid >> 3) & 1, sub = bid >> 4;
  const int bt = sub & 1, gt = sub >> 1;
  const int rowBase = bt*128 + w*16;                // wave's 16 A-rows
  const int hc0 = gt*32;                            // block's hcol base
  const size_t sOff = (size_t)s*65536;
  u16* wscr = scratch + w*512;

  auto offA = [](int ss, int bb_){ return (unsigned)((ss*2 + bb_)*64); };
  auto offB = [](int ss, int bb_){ return (unsigned)(1024 + (ss*2 + bb_)*64); };
  if (tid == 0){
    pollE[0] = offA(s, bt); pollE[1] = offB(s, bt);
    for (int i = 2; i < 16; ++i) pollE[i] = pollE[0];
    unsigned pad;
    if (fam == 0){
      pad = offA(s, bt);
      pollD[0] = pad;
      pollD[1] = offB(s, 0); pollD[2] = offB(s, 1);
      pollD[3] = (s > 0) ? offB(s-1, 0) : pad;
      pollD[4] = (s > 0) ? offB(s-1, 1) : pad;
      for (int i = 5; i < 16; ++i) pollD[i] = pad;
    } else {
      pad = offA(s, 0);
      pollD[0] = pad;          pollD[1] = offA(s, 1);
      pollD[2] = offB(s, 0);   pollD[3] = offB(s, 1);
      pollD[4] = (s < 7) ? offA(s+1, 0) : pad;
      pollD[5] = (s < 7) ? offA(s+1, 1) : pad;
      pollD[6] = (s < 7) ? offB(s+1, 0) : pad;
      pollD[7] = (s < 7) ? offB(s+1, 1) : pad;
      pollD[8] = (s > 0) ? offB(s-1, 0) : pad;   // lev WAR closure (only delta vs R10)
      pollD[9] = (s > 0) ? offB(s-1, 1) : pad;
      for (int i = 10; i < 16; ++i) pollD[i] = pad;
    }
  }
  unsigned* myCnt = A.bar + ((fam == 0) ? offA(s, bt) : offB(s, bt));
  __syncthreads();

  float cR[8];
#pragma unroll
  for (int i = 0; i < 8; ++i) cR[i] = 0.f;

  unsigned gen = 0;
  const int gb0[3] = {0, 90, 104};

  for (int ph = 0; ph < 3; ++ph){
    const int T = A.T[ph];
    const int IN = A.IN[ph];
    const bool dec = (ph > 0);
    const int SS = T + (dec ? 3 : 1);
    const int tdb = (ph == 2) ? 14 : 0;

    float bb[4][2];
    if (fam == 0){
      pinW256(A.whh0[ph] + (size_t)s*262144, gt, lds0, tid);
      pinWp  (A.wih0p[ph] + (size_t)s*32768, gt, lds1, tid);
      pinWin (A.winH, s, gt, ldsWin, tid);
      const float* bS = A.b0[ph] + s*1024;
#pragma unroll
      for (int g = 0; g < 4; ++g){ bb[g][0] = bS[g*256 + hc0 + l15]; bb[g][1] = bS[g*256 + hc0 + 16 + l15]; }
    } else {
      pinW256(A.whh1[ph] + (size_t)s*262144, gt, lds0, tid);
      pinW256(A.wih1[ph] + (size_t)s*262144, gt, lds1, tid);
      const float* bS = A.b1[ph] + s*1024;
#pragma unroll
      for (int g = 0; g < 4; ++g){ bb[g][0] = bS[g*256 + hc0 + l15]; bb[g][1] = bS[g*256 + hc0 + 16 + l15]; }
    }
    __syncthreads();

    for (int ss = 0; ss < SS; ++ss){
      // ---- POLL (IC counters, R8-proven; 16 parallel checks) ----
      if (w == 0){
        unsigned off = (dec ? pollD : pollE)[lane & 15];
        const unsigned* p = A.bar + off;
        unsigned tgt = 8u * gen;
        for (;;){
          unsigned v = ld_spin_ic(p);
          if (__all((int)(v >= tgt))) break;
          __builtin_amdgcn_s_sleep(1);
        }
      }
      __syncthreads();

      if (fam == 0){
        // ---- L0(t=ss) ----
        if (ss < T){
          int t = ss, g0 = gb0[ph] + t;
          const u16* h0in = ((g0 & 1) ? A.h0b : A.h0a) + sOff;
          u16* h0out = ((g0 & 1) ? A.h0a : A.h0b) + sOff;
          f32x4 acc[8];
#pragma unroll
          for (int q = 0; q < 8; ++q) acc[q] = (f32x4){0.f,0.f,0.f,0.f};
          u32x4 a[8];
          ldg8_nw(a, h0in + (size_t)(rowBase + l15)*256 + l4*8);
          FragU xa;
#pragma unroll
          for (int e = 0; e < 8; ++e) xa.u[e] = 0;
          {
            const float* xrow = A.x[ph] + ((size_t)(s*256 + rowBase + l15)*T + t)*IN;
            if (IN == 16){
              if (l4 < 2){
                float4 u0 = reinterpret_cast<const float4*>(xrow)[l4*2];
                float4 u1 = reinterpret_cast<const float4*>(xrow)[l4*2+1];
                xa.u[0]=f2bf(u0.x); xa.u[1]=f2bf(u0.y); xa.u[2]=f2bf(u0.z); xa.u[3]=f2bf(u0.w);
                xa.u[4]=f2bf(u1.x); xa.u[5]=f2bf(u1.y); xa.u[6]=f2bf(u1.z); xa.u[7]=f2bf(u1.w);
              }
            } else {
              if (l4 == 0){
                float4 u0 = *reinterpret_cast<const float4*>(xrow);
                xa.u[0]=f2bf(u0.x); xa.u[1]=f2bf(u0.y); xa.u[2]=f2bf(u0.z); xa.u[3]=f2bf(u0.w);
              }
            }
          }
          wait_vm0();
          seg_mfma8(lds0, a, acc, l15, l4);
#pragma unroll
          for (int q = 0; q < 8; ++q){
            int n = (q >> 1)*32 + (q & 1)*16 + l15;
            int sl = l4 ^ (n & 3);
            acc[q] = __builtin_amdgcn_mfma_f32_16x16x32_bf16(
                xa.v, *reinterpret_cast<const bf16x8*>(lds1 + n*32 + sl*8), acc[q], 0,0,0);
          }
          cell_epi(bb, cR, h0out, rowBase, hc0, lane, wscr, acc);
        }
        // ---- hinG(t=ss-2): bf16 out (N=32 tile of winH) ----
        if (dec){
          int th = ss - 2;
          if (th >= 0 && th < T){
            int g = gb0[ph] + th, tdec = tdb + th;
            const u16* h1cur = ((g & 1) ? A.h1a : A.h1b) + sOff;
            u16* hg = ((tdec & 1) ? A.hgB : A.hgA) + sOff;
            f32x4 a2[2];
            a2[0] = (f32x4){0.f,0.f,0.f,0.f}; a2[1] = a2[0];
            u32x4 a[8];
            ldg8_nw(a, h1cur + (size_t)(rowBase + l15)*256 + l4*8);
            wait_vm0();
#pragma unroll
            for (int ck = 0; ck < 8; ++ck){
              FragU af; af.q = a[ck];
#pragma unroll
              for (int q = 0; q < 2; ++q){
                int n = q*16 + l15;
                int sl = (ck*4 + l4) ^ (n & 7);
                a2[q] = __builtin_amdgcn_mfma_f32_16x16x32_bf16(
                    af.v, *reinterpret_cast<const bf16x8*>(ldsWin + n*256 + sl*8), a2[q], 0,0,0);
              }
            }
#pragma unroll
            for (int q = 0; q < 2; ++q)
#pragma unroll
              for (int r = 0; r < 4; ++r)
                wscr[(l4*4 + r)*32 + q*16 + l15] = f2bf(a2[q][r]);
            asm volatile("s_waitcnt lgkmcnt(0)" ::: "memory");
            u32x4 v = *reinterpret_cast<const u32x4*>(wscr + (lane>>2)*32 + (lane&3)*8);
            stg16_sc(hg + (size_t)(rowBase + (lane>>2))*256 + hc0 + (lane&3)*8, v);
          }
        }
      } else {
        // ---- L1(t=ss-1): both 8-load batches in flight, counted waits ----
        int t = ss - 1;
        if (t >= 0 && t < T){
          int g = gb0[ph] + t;
          const u16* h1in = ((g & 1) ? A.h1b : A.h1a) + sOff;
          u16* h1out = ((g & 1) ? A.h1a : A.h1b) + sOff;
          const u16* h0cur = ((g & 1) ? A.h0a : A.h0b) + sOff;
          f32x4 acc[8];
#pragma unroll
          for (int q = 0; q < 8; ++q) acc[q] = (f32x4){0.f,0.f,0.f,0.f};
          u32x4 a0[8], a1[8];
          ldg8_nw(a0, h1in + (size_t)(rowBase + l15)*256 + l4*8);
          ldg8_nw(a1, h0cur + (size_t)(rowBase + l15)*256 + l4*8);
          wait_vm8();
          seg_mfma8(lds0, a0, acc, l15, l4);
          wait_vm0();
          seg_mfma8(lds1, a1, acc, l15, l4);
          cell_epi(bb, cR, h1out, rowBase, hc0, lane, wscr, acc);
        }
        // ---- graph(t=ss-3) ----
        if (dec){
          int tgl = ss - 3;
          if (tgl >= 0 && tgl < T){
            int tg = tdb + tgl;
            const u16* hgb16 = (tg & 1) ? A.hgB : A.hgA;
            const float* levc = (tg & 1) ? A.levB : A.levA;
            float* levn = (tg & 1) ? A.levA : A.levB;
            int brow0 = sub*16;
            f32x4 acc[2];
            acc[0] = (f32x4){0.f,0.f,0.f,0.f}; acc[1] = acc[0];
            for (int ts = 0; ts < 8; ++ts){
              float av = A.adj[s*8 + ts];
              if (av == 0.f) continue;
              float lv;
              u32x4 hv[8];
              ldg8f_sc(hv, lv, hgb16 + (size_t)ts*65536 + (size_t)(brow0 + l15)*256 + l4*8,
                       levc + ts*256 + brow0 + l15);
              const float* wlB = A.winLev + ts*256 + l4*8;
#pragma unroll
              for (int ck = 0; ck < 8; ++ck){
                FragU hr; hr.q = hv[ck];
                float4 w0 = *reinterpret_cast<const float4*>(wlB + ck*32);
                float4 w1 = *reinterpret_cast<const float4*>(wlB + ck*32 + 4);
                float wls[8] = {w0.x,w0.y,w0.z,w0.w,w1.x,w1.y,w1.z,w1.w};
                FragU af;
#pragma unroll
                for (int e = 0; e < 8; ++e)
                  af.u[e] = f2bf(fmaxf(bf2f(hr.u[e]) + lv*wls[e], 0.f) * av);
#pragma unroll
                for (int q = 0; q < 2; ++q){
                  int n = (w*2+q)*16 + l15;
                  bf16x8 bfr = *reinterpret_cast<const bf16x8*>(A.gT + (size_t)n*256 + ck*32 + l4*8);
                  acc[q] = __builtin_amdgcn_mfma_f32_16x16x32_bf16(af.v, bfr, acc[q], 0,0,0);
                }
              }
            }
            float part[4] = {0.f,0.f,0.f,0.f};
            const float* woS = A.wout + s*256;
#pragma unroll
            for (int q = 0; q < 2; ++q){
              int m = (w*2+q)*16 + l15;
              float gbv = A.gb[m], wo = woS[m];
#pragma unroll
              for (int r = 0; r < 4; ++r) part[r] += fmaxf(acc[q][r] + gbv, 0.f) * wo;
            }
#pragma unroll
            for (int d = 1; d < 16; d <<= 1)
#pragma unroll
              for (int r = 0; r < 4; ++r) part[r] += __shfl_xor(part[r], d, 64);
            if (l15 == 0)
#pragma unroll
              for (int r = 0; r < 4; ++r) red[w][l4*4+r] = part[r];
            __syncthreads();
            if (tid < 16){
              float flow = 0.f;
#pragma unroll
              for (int ww = 0; ww < 8; ++ww) flow += red[ww][tid];
              int b = brow0 + tid;
              A.out[(size_t)b*720 + tg*8 + s] = flow;
              float lvo = ldf_sc(levc + s*256 + b);
              stf_sc(levn + s*256 + b, lvo + flow * A.fstd[s]);
            }
          }
        }
      }
      // ---- DRAIN + SIGNAL ----
      asm volatile("s_waitcnt vmcnt(0)" ::: "memory");
      __syncthreads();
      if (tid == 0) __hip_atomic_fetch_add(myCnt, 1u, RLX, AGT);
      ++gen;
    }
  }
}

// ------------------------------------------------------------------
// Preamble conversion kernels
// ------------------------------------------------------------------
struct Cvt9Args { const float* s[9]; u16* d[9]; };
__global__ void k_cvt9(Cvt9Args A){
  size_t i = (size_t)blockIdx.x*256 + threadIdx.x;
  int t = (int)(i >> 21); size_t r = i & 2097151u;
  A.d[t][r] = f2bf(A.s[t][r]);
}
struct Pad3Args { const float* s[3]; u16* d[3]; int kx[3]; };
__global__ void k_pad3(Pad3Args A){
  size_t i = (size_t)blockIdx.x*256 + threadIdx.x;
  int t = (int)(i >> 18); int r = (int)(i & 262143u);
  int row = r >> 5, col = r & 31;
  int kx = A.kx[t];
  A.d[t][r] = (col < kx) ? f2bf(A.s[t][(size_t)row*kx + col]) : (u16)0;
}
__global__ void k_win(const float* win, u16* winH, float* winLev){
  size_t i = (size_t)blockIdx.x*256 + threadIdx.x;
  if (i >= (size_t)8*256*257) return;
  int k = (int)(i % 257); size_t sm = i / 257;
  float v = win[i];
  if (k < 256) winH[sm*256 + k] = f2bf(v);
  else winLev[sm] = v;
}
__global__ void k_gt(const float* gW, u16* gT){
  int i = blockIdx.x*256 + threadIdx.x;
  int h = i >> 8, k = i & 255;
  gT[(size_t)k*256 + h] = f2bf(gW[i]);
}

// ------------------------------------------------------------------
// Host
// ------------------------------------------------------------------
extern "C" void kernel_launch(void* const* d_in, const int* in_sizes, int n_in,
                              void* d_out, int out_size, void* d_ws, size_t ws_size,
                              hipStream_t stream){
  const float* x_d    = (const float*)d_in[0];
  const float* x_f    = (const float*)d_in[1];
  const float* x_ff   = (const float*)d_in[2];
  const float* level0 = (const float*)d_in[3];
  const float* fstd   = (const float*)d_in[4];
  const float* adj    = (const float*)d_in[5];
  const float* W[18];
  for (int i = 0; i < 18; i++) W[i] = (const float*)d_in[6+i];
  const float* win  = (const float*)d_in[24];
  const float* wout = (const float*)d_in[25];
  const float* gW   = (const float*)d_in[26];
  const float* gb   = (const float*)d_in[27];

  char* base = (char*)d_ws;
  size_t off = 0;
  auto alloc = [&](size_t bytes)->void*{
    void* r = base + off;
    off += (bytes + 255) & ~(size_t)255;
    return r;
  };
  u16* wb[9]; for (int i = 0; i < 9; i++) wb[i] = (u16*)alloc((size_t)2097152*2);
  u16* wp[3]; for (int i = 0; i < 3; i++) wp[i] = (u16*)alloc((size_t)262144*2);
  u16* winH = (u16*)alloc((size_t)524288*2);
  u16* gT   = (u16*)alloc((size_t)65536*2);
  float* winLev = (float*)alloc((size_t)2048*4);
  u16* h0a = (u16*)alloc((size_t)524288*2);
  u16* h0b = (u16*)alloc((size_t)524288*2);
  u16* h1a = (u16*)alloc((size_t)524288*2);
  u16* h1b = (u16*)alloc((size_t)524288*2);
  u16* hgA = (u16*)alloc((size_t)524288*2);
  u16* hgB = (u16*)alloc((size_t)524288*2);
  float* levA = (float*)alloc((size_t)2048*4);
  float* levB = (float*)alloc((size_t)2048*4);
  unsigned* bar = (unsigned*)alloc(16384);

  Cvt9Args c9;
  const float* c9s[9] = { W[1], W[4], W[3],  W[7], W[10], W[9],  W[13], W[16], W[15] };
  for (int i = 0; i < 9; i++){ c9.s[i] = c9s[i]; c9.d[i] = wb[i]; }
  k_cvt9<<<73728,256,0,stream>>>(c9);

  Pad3Args p3;
  const float* p3s[3] = { W[0], W[6], W[12] };
  int kx3[3] = {16,16,4};
  for (int i = 0; i < 3; i++){ p3.s[i] = p3s[i]; p3.d[i] = wp[i]; p3.kx[i] = kx3[i]; }
  k_pad3<<<3072,256,0,stream>>>(p3);

  k_win<<<2057,256,0,stream>>>(win, winH, winLev);
  k_gt<<<256,256,0,stream>>>(gW, gT);

  (void)hipMemsetAsync(h0a, 0, (size_t)524288*2, stream);
  (void)hipMemsetAsync(h1a, 0, (size_t)524288*2, stream);
  (void)hipMemsetAsync(bar, 0, 16384, stream);
  (void)hipMemcpyAsync(levA, level0, (size_t)2048*4, hipMemcpyDeviceToDevice, stream);

  PArgs A;
  for (int ph = 0; ph < 3; ++ph){
    A.whh0[ph] = wb[ph*3+0];
    A.whh1[ph] = wb[ph*3+1];
    A.wih1[ph] = wb[ph*3+2];
    A.wih0p[ph] = wp[ph];
  }
  A.b0[0] = W[2];  A.b1[0] = W[5];
  A.b0[1] = W[8];  A.b1[1] = W[11];
  A.b0[2] = W[14]; A.b1[2] = W[17];
  A.x[0] = x_d; A.x[1] = x_f; A.x[2] = x_ff;
  A.winH = winH; A.winLev = winLev;
  A.gT = gT; A.gb = gb; A.wout = wout; A.adj = adj; A.fstd = fstd;
  A.h0a = h0a; A.h0b = h0b; A.h1a = h1a; A.h1b = h1b;
  A.hgA = hgA; A.hgB = hgB;
  A.levA = levA; A.levB = levB;
  A.out = (float*)d_out;
  A.bar = bar;
  A.T[0] = 90; A.T[1] = 14; A.T[2] = 76;
  A.IN[0] = 16; A.IN[1] = 16; A.IN[2] = 4;

  const int smemBytes = 139776;
  (void)hipFuncSetAttribute((const void*)k_persist, hipFuncAttributeMaxDynamicSharedMemorySize, smemBytes);
  k_persist<<<dim3(256), dim3(512), smemBytes, stream>>>(A);
}